// Round 2
// baseline (1674.257 us; speedup 1.0000x reference)
//
#include <hip/hip_runtime.h>

typedef unsigned short u16;
typedef __attribute__((ext_vector_type(4))) float f4;
typedef __attribute__((ext_vector_type(8))) __bf16 bf16x8;
typedef __attribute__((ext_vector_type(4))) float f32x4;

#define D_MODEL 2048
#define D_SSM 4096
#define D_STATE 128
#define NHEADS 64
#define HEADDIM 64
#define CHUNK 64
#define LTOT 4096
#define NB 2
#define CONV_DIM 4352
#define XBC_LD 4480   // 4352 conv channels + 64 dt + 64 pad, multiple of 128

__device__ inline float bf2f(unsigned v) { return __uint_as_float(v << 16); }
__device__ inline u16 f2bf(float f) {
    unsigned u = __float_as_uint(f);
    unsigned r = (u + 0x7fffu + ((u >> 16) & 1u)) >> 16;
    return (u16)r;
}
__device__ inline unsigned pack2(float a, float b) {
    return (unsigned)f2bf(a) | ((unsigned)f2bf(b) << 16);
}
__device__ inline void gload_lds16(const void* g, void* l) {
    __builtin_amdgcn_global_load_lds((const __attribute__((address_space(1))) void*)g,
                                     (__attribute__((address_space(3))) void*)l, 16, 0, 0);
}

// ---------------- f32 -> bf16 cast ----------------
__global__ __launch_bounds__(256) void tobf16_kernel(const float* __restrict__ src,
                                                     u16* __restrict__ dst, int n4) {
    int i = blockIdx.x * 256 + threadIdx.x;
    if (i < n4) {
        f4 v = ((const f4*)src)[i];
        uint2 pk;
        pk.x = pack2(v[0], v[1]);
        pk.y = pack2(v[2], v[3]);
        ((uint2*)dst)[i] = pk;
    }
}

// W_in (8512 x 2048) f32 -> win_bf (8576 x 2048) bf16, pad rows zero
__global__ __launch_bounds__(256) void winpad_kernel(const float* __restrict__ src,
                                                     u16* __restrict__ dst) {
    int i = blockIdx.x * 256 + threadIdx.x;  // over 8576*2048/4
    if (i >= (8576 * 2048 / 4)) return;
    int col4 = i & 511;
    int row = i >> 9;
    f4 v = {0.f, 0.f, 0.f, 0.f};
    if (row < 8512) v = ((const f4*)src)[row * 512 + col4];
    uint2 pk;
    pk.x = pack2(v[0], v[1]);
    pk.y = pack2(v[2], v[3]);
    ((uint2*)dst)[i] = pk;
}

// ---------------- GEMM: C[m,n] = sum_k A[m,k]*B[n,k]; bf16 in; f32 or bf16 out ----
// 128x128 tile, BK=32, 256 threads (2x2 waves of 64x64), mfma 16x16x32. LDS 16KB.
template <int OUT_BF16>
__global__ __launch_bounds__(256) void gemm_bt(const u16* __restrict__ A,
                                               const u16* __restrict__ B,
                                               void* __restrict__ Cp, int K, int ldC) {
    __shared__ u16 As[128 * 32];
    __shared__ u16 Bsm[128 * 32];
    int t = threadIdx.x, w = t >> 6, lane = t & 63;
    int blockM = blockIdx.y * 128, blockN = blockIdx.x * 128;
    int wm = (w & 1) * 64, wn = (w >> 1) * 64;

    const u16* Ab = A + (size_t)(blockM + 32 * w + (lane >> 2)) * K + (lane & 3) * 8;
    const u16* Bb = B + (size_t)(blockN + 32 * w + (lane >> 2)) * K + (lane & 3) * 8;
    u16* AsW = As + w * 1024;
    u16* BsW = Bsm + w * 1024;

    f32x4 acc[4][4] = {};
    const bf16x8* As8 = (const bf16x8*)As;
    const bf16x8* Bs8 = (const bf16x8*)Bsm;
    int aoff = (wm + (lane & 15)) * 4 + (lane >> 4);
    int boff = (wn + (lane & 15)) * 4 + (lane >> 4);

    for (int k0 = 0; k0 < K; k0 += 32) {
        const u16* Ag = Ab + k0;
        const u16* Bg = Bb + k0;
        gload_lds16(Ag, AsW);
        gload_lds16(Ag + (size_t)16 * K, AsW + 512);
        gload_lds16(Bg, BsW);
        gload_lds16(Bg + (size_t)16 * K, BsW + 512);
        __syncthreads();
        bf16x8 af[4], bfv[4];
#pragma unroll
        for (int i = 0; i < 4; i++) af[i] = As8[aoff + 64 * i];
#pragma unroll
        for (int j = 0; j < 4; j++) bfv[j] = Bs8[boff + 64 * j];
#pragma unroll
        for (int i = 0; i < 4; i++)
#pragma unroll
            for (int j = 0; j < 4; j++)
                acc[i][j] = __builtin_amdgcn_mfma_f32_16x16x32_bf16(af[i], bfv[j], acc[i][j], 0, 0, 0);
        __syncthreads();
    }
    int rbase = blockM + wm + (lane >> 4) * 4;
    int cbase = blockN + wn + (lane & 15);
    if (OUT_BF16) {
        u16* C = (u16*)Cp;
#pragma unroll
        for (int i = 0; i < 4; i++)
#pragma unroll
            for (int j = 0; j < 4; j++)
#pragma unroll
                for (int r = 0; r < 4; r++)
                    C[(size_t)(rbase + 16 * i + r) * ldC + cbase + 16 * j] = f2bf(acc[i][j][r]);
    } else {
        float* C = (float*)Cp;
#pragma unroll
        for (int i = 0; i < 4; i++)
#pragma unroll
            for (int j = 0; j < 4; j++)
#pragma unroll
                for (int r = 0; r < 4; r++)
                    C[(size_t)(rbase + 16 * i + r) * ldC + cbase + 16 * j] = acc[i][j][r];
    }
}

// ---------------- depthwise causal conv(4) + bias + silu; bf16 in/out ----------------
__global__ __launch_bounds__(256) void conv_kernel(const u16* __restrict__ xbcdt,
                                                   const float* __restrict__ conv_w,
                                                   const float* __restrict__ conv_b,
                                                   u16* __restrict__ convO) {
    int ch = blockIdx.x * 256 + threadIdx.x;  // 17*256 = 4352 exact
    int row = blockIdx.y;                     // 8192
    int l = row & (LTOT - 1);
    f4 w = *(const f4*)&conv_w[ch * 4];
    float acc = conv_b[ch];
#pragma unroll
    for (int k = 0; k < 4; ++k) {
        int ls = l - 3 + k;
        if (ls >= 0) acc += bf2f(xbcdt[(size_t)(row - 3 + k) * XBC_LD + ch]) * w[k];
    }
    convO[(size_t)row * CONV_DIM + ch] = f2bf(acc / (1.f + __expf(-acc)));
}

// ---------------- dt = softplus(raw + bias) -> dtp[row][h] f32 ----------------
__global__ __launch_bounds__(256) void dt_kernel(const u16* __restrict__ xbcdt,
                                                 const float* __restrict__ dt_bias,
                                                 float* __restrict__ dtp) {
    int idx = blockIdx.x * 256 + threadIdx.x;  // 8192*64
    if (idx >= NB * LTOT * NHEADS) return;
    int row = idx >> 6, h = idx & 63;
    float x = bf2f(xbcdt[(size_t)row * XBC_LD + CONV_DIM + h]) + dt_bias[h];
    dtp[idx] = (x > 15.f) ? x : log1pf(__expf(x));
}

// ---------------- CB[l,s] = sum_n C[l,n]*B[s,n] per (b,c) -> CBb f32 ----------------
__global__ __launch_bounds__(256) void cb_kernel(const u16* __restrict__ convO,
                                                 float* __restrict__ CBb) {
    __shared__ u16 Bt[128 * 68];  // [n][s]
    __shared__ u16 Ct[128 * 68];  // [n][l]
    int bc = blockIdx.x;
    int c = bc & 63, b = bc >> 6;
    int rowbase = b * LTOT + c * CHUNK;
    int t = threadIdx.x;
#pragma unroll
    for (int i = 0; i < 32; i++) {
        int idx = i * 256 + t;
        int s = idx >> 7, n = idx & 127;
        Bt[n * 68 + s] = convO[(size_t)(rowbase + s) * CONV_DIM + D_SSM + n];
        Ct[n * 68 + s] = convO[(size_t)(rowbase + s) * CONV_DIM + D_SSM + D_STATE + n];
    }
    __syncthreads();
    int sq = t & 15, lq = t >> 4;
    f4 acc[4] = {};
#pragma unroll 4
    for (int n = 0; n < 128; n++) {
        ushort4 bv = *(const ushort4*)&Bt[n * 68 + sq * 4];
        ushort4 cv = *(const ushort4*)&Ct[n * 68 + lq * 4];
        f4 bf;
        bf[0] = bf2f(bv.x); bf[1] = bf2f(bv.y); bf[2] = bf2f(bv.z); bf[3] = bf2f(bv.w);
        float c0 = bf2f(cv.x), c1 = bf2f(cv.y), c2 = bf2f(cv.z), c3 = bf2f(cv.w);
        acc[0] += c0 * bf; acc[1] += c1 * bf; acc[2] += c2 * bf; acc[3] += c3 * bf;
    }
    float* outb = CBb + (size_t)bc * 4096;
#pragma unroll
    for (int j = 0; j < 4; j++) *(f4*)&outb[(lq * 4 + j) * 64 + sq * 4] = acc[j];
}

// ---------------- fused SSM: Y_diag + Y_off + D*x, state carried in registers ------
// grid 512 = (b 2) x (h 64) x (pg 4); block 256; sequential over 64 chunks.
__global__ __launch_bounds__(256) void ssm_fused(const u16* __restrict__ convO,
                                                 const float* __restrict__ dtp,
                                                 const float* __restrict__ CBb,
                                                 const float* __restrict__ A_log,
                                                 const float* __restrict__ Dvec,
                                                 u16* __restrict__ ybf) {
    __shared__ float xs[64 * 16];    // [l][p] f32, 4KB
    __shared__ u16 Bsm[64 * 136];    // [l][n] bf16 padded, 17408B
    __shared__ u16 Csm[64 * 136];    // 17408B
    __shared__ float G[64 * 68];     // [l][s] f32, 17408B
    __shared__ u16 Slb[128 * 20];    // [n][p] bf16 padded, 5120B
    __shared__ float dts_s[64], acs[64], w_l[64], e_l[64];

    int t = threadIdx.x;
    int z = blockIdx.x;
    int pg = z & 3, h = (z >> 2) & 63, b = z >> 8;
    int p0 = pg * 16;
    float Ah = -__expf(A_log[h]);
    float Dh = Dvec[h];

    int nq = t & 31, pr = t >> 5;  // S ownership: n = nq*4+j, p = pr*2 + {0,1}
    int ly = t >> 2, pq = t & 3;   // y ownership: l = ly, p = pq*4..+3
    int smax = (t >> 6) * 16 + 15; // wave-uniform Y_diag bound (G is 0 above diag)

    f4 S0 = {0.f, 0.f, 0.f, 0.f}, S1 = {0.f, 0.f, 0.f, 0.f};
    const float* CBbase = CBb + (size_t)(b * 64) * 4096;

    for (int c = 0; c < 64; ++c) {
        int rowbase = b * LTOT + c * CHUNK;
        __syncthreads();
        // ---- phase 1: stage everything ----
        if (t < 64) {
            float dtv = dtp[(size_t)(rowbase + t) * 64 + h];
            float v = dtv * Ah;
#pragma unroll
            for (int off = 1; off < 64; off <<= 1) {
                float pv = __shfl_up(v, off, 64);
                if (t >= off) v += pv;
            }
            dts_s[t] = dtv;
            acs[t] = v;
        }
        {
            int row = t >> 2, pi = (t & 3) * 4;
            ushort4 xv = *(const ushort4*)&convO[(size_t)(rowbase + row) * CONV_DIM + h * 64 + p0 + pi];
            f4 xf = {bf2f(xv.x), bf2f(xv.y), bf2f(xv.z), bf2f(xv.w)};
            *(f4*)&xs[row * 16 + pi] = xf;
        }
#pragma unroll
        for (int i = 0; i < 4; ++i) {
            int idx = i * 256 + t;  // 1024 uint4 slots over [64][128] bf16
            int row = idx >> 4, c8 = idx & 15;
            uint4 bv = *(const uint4*)&convO[(size_t)(rowbase + row) * CONV_DIM + D_SSM + c8 * 8];
            *(uint4*)&Bsm[row * 136 + c8 * 8] = bv;
            uint4 cv = *(const uint4*)&convO[(size_t)(rowbase + row) * CONV_DIM + D_SSM + D_STATE + c8 * 8];
            *(uint4*)&Csm[row * 136 + c8 * 8] = cv;
        }
#pragma unroll
        for (int j = 0; j < 4; ++j) {  // stage entering state S -> LDS bf16
            int n = nq * 4 + j;
            *(unsigned*)&Slb[n * 20 + pr * 2] = pack2(S0[j], S1[j]);
        }
        __syncthreads();
        // ---- phase 2: w/e factors, G fill, Y_off partials ----
        if (t < 64) {
            float al = acs[63];
            w_l[t] = dts_s[t] * __expf(al - acs[t]);
            e_l[t] = __expf(acs[t]);
        }
        {
            const float* CBg = CBbase + (size_t)c * 4096;
#pragma unroll
            for (int i = 0; i < 16; ++i) {
                int idx = i * 256 + t;
                int l = idx >> 6, s = idx & 63;
                float g = 0.f;
                if (s <= l) g = CBg[idx] * __expf(acs[l] - acs[s]) * dts_s[s];
                G[l * 68 + s] = g;
            }
        }
        f4 accoff = {0.f, 0.f, 0.f, 0.f};
#pragma unroll 4
        for (int n4 = 0; n4 < 32; ++n4) {
            ushort4 cv = *(const ushort4*)&Csm[ly * 136 + n4 * 4];
#pragma unroll
            for (int j = 0; j < 4; ++j) {
                int n = n4 * 4 + j;
                ushort4 sv = *(const ushort4*)&Slb[n * 20 + pq * 4];
                f4 sf = {bf2f(sv.x), bf2f(sv.y), bf2f(sv.z), bf2f(sv.w)};
                float cf = bf2f(((const u16*)&cv)[j]);
                accoff += cf * sf;
            }
        }
        __syncthreads();
        // ---- phase 3: Y_diag + write y; state update ----
        f4 xl = *(const f4*)&xs[ly * 16 + pq * 4];
        f4 acc = Dh * xl;
#pragma unroll 4
        for (int s = 0; s <= smax; ++s) {
            float g = G[ly * 68 + s];
            f4 xv = *(const f4*)&xs[s * 16 + pq * 4];
            acc += g * xv;
        }
        f4 yout = acc + e_l[ly] * accoff;
        uint2 pk;
        pk.x = pack2(yout[0], yout[1]);
        pk.y = pack2(yout[2], yout[3]);
        *(uint2*)&ybf[(size_t)(rowbase + ly) * D_SSM + h * 64 + p0 + pq * 4] = pk;

        float cd = e_l[63];
        S0 *= cd;
        S1 *= cd;
#pragma unroll 4
        for (int l = 0; l < 64; ++l) {
            ushort4 bv = *(const ushort4*)&Bsm[l * 136 + nq * 4];
            float wl = w_l[l];
            float x0 = xs[l * 16 + pr * 2] * wl;
            float x1 = xs[l * 16 + pr * 2 + 1] * wl;
            f4 bf;
            bf[0] = bf2f(bv.x); bf[1] = bf2f(bv.y); bf[2] = bf2f(bv.z); bf[3] = bf2f(bv.w);
            S0 += x0 * bf;
            S1 += x1 * bf;
        }
    }
}

// ---------------- gate (silu(z)) + RMSNorm, in-place on y_bf ----------------
__global__ __launch_bounds__(256) void gate_norm(const u16* __restrict__ zbf,
                                                 const float* __restrict__ normw,
                                                 u16* __restrict__ ybf) {
    int row = blockIdx.x, t = threadIdx.x;
    const uint2* y2 = (const uint2*)(ybf + (size_t)row * D_SSM);
    const uint2* z2 = (const uint2*)(zbf + (size_t)row * D_SSM);
    f4 yg[4];
    float ss = 0.f;
#pragma unroll
    for (int i = 0; i < 4; ++i) {
        int idx = i * 256 + t;
        uint2 yv = y2[idx], zv = z2[idx];
        float ya[4] = {bf2f(yv.x & 0xffffu), bf2f(yv.x >> 16), bf2f(yv.y & 0xffffu), bf2f(yv.y >> 16)};
        float za[4] = {bf2f(zv.x & 0xffffu), bf2f(zv.x >> 16), bf2f(zv.y & 0xffffu), bf2f(zv.y >> 16)};
        f4 g;
#pragma unroll
        for (int k = 0; k < 4; ++k) {
            float sz = za[k] / (1.f + __expf(-za[k]));
            g[k] = ya[k] * sz;
            ss += g[k] * g[k];
        }
        yg[i] = g;
    }
#pragma unroll
    for (int off = 32; off; off >>= 1) ss += __shfl_down(ss, off, 64);
    __shared__ float red[4];
    if ((t & 63) == 0) red[t >> 6] = ss;
    __syncthreads();
    float tot = red[0] + red[1] + red[2] + red[3];
    float scale = rsqrtf(tot / (float)D_SSM + 1e-5f);
    const f4* nw4 = (const f4*)normw;
    uint2* out = (uint2*)(ybf + (size_t)row * D_SSM);
#pragma unroll
    for (int i = 0; i < 4; ++i) {
        int idx = i * 256 + t;
        f4 v = yg[i] * scale * nw4[idx];
        uint2 pk;
        pk.x = pack2(v[0], v[1]);
        pk.y = pack2(v[2], v[3]);
        out[idx] = pk;
    }
}

// ---------------- launch ----------------
extern "C" void kernel_launch(void* const* d_in, const int* in_sizes, int n_in,
                              void* d_out, int out_size, void* d_ws, size_t ws_size,
                              hipStream_t stream) {
    const float* u = (const float*)d_in[0];
    const float* W_in = (const float*)d_in[1];
    const float* conv_w = (const float*)d_in[2];
    const float* conv_b = (const float*)d_in[3];
    const float* dt_bias = (const float*)d_in[4];
    const float* A_log = (const float*)d_in[5];
    const float* Dv = (const float*)d_in[6];
    const float* normw = (const float*)d_in[7];
    const float* W_out = (const float*)d_in[8];
    float* out = (float*)d_out;
    char* ws = (char*)d_ws;

    // workspace layout (total 216,006,656 B ~= 206 MiB)
    u16* z_bf = (u16*)(ws + 0ULL);              //  8192x4096 bf16 = 67,108,864
    u16* xbcdt = (u16*)(ws + 67108864ULL);      //  8192x4480 bf16 = 73,400,320
    u16* y_bf = xbcdt;                          //  overlay: 8192x4096 bf16 (xbcdt dead after conv+dt)
    u16* convO = (u16*)(ws + 140509184ULL);     //  8192x4352 bf16 = 71,303,168
    u16* u_bf = convO;                          //  overlay: 33,554,432 (dead before conv writes)
    u16* win_bf = (u16*)(ws + 174063616ULL);    //  overlay: 35,127,296 (ends 209,190,912)
    u16* wout_bf = convO;                       //  overlay: 16,777,216 (after ssm_fused)
    float* dtp = (float*)(ws + 211812352ULL);   //  8192x64 f32 = 2,097,152
    float* CBb = (float*)(ws + 213909504ULL);   //  128x64x64 f32 = 2,097,152

    tobf16_kernel<<<16384, 256, 0, stream>>>(u, u_bf, 4194304);
    winpad_kernel<<<17152, 256, 0, stream>>>(W_in, win_bf);
    // in-proj split: z part (N=4096), then xBC+dt part (N=4480 incl. zero pad)
    gemm_bt<1><<<dim3(32, 64), 256, 0, stream>>>(u_bf, win_bf, z_bf, 2048, 4096);
    gemm_bt<1><<<dim3(35, 64), 256, 0, stream>>>(u_bf, win_bf + (size_t)4096 * 2048, xbcdt, 2048, XBC_LD);
    conv_kernel<<<dim3(17, 8192), 256, 0, stream>>>(xbcdt, conv_w, conv_b, convO);
    dt_kernel<<<2048, 256, 0, stream>>>(xbcdt, dt_bias, dtp);
    cb_kernel<<<128, 256, 0, stream>>>(convO, CBb);
    ssm_fused<<<512, 256, 0, stream>>>(convO, dtp, CBb, A_log, Dv, y_bf);
    tobf16_kernel<<<8192, 256, 0, stream>>>(W_out, wout_bf, 2097152);
    gate_norm<<<8192, 256, 0, stream>>>(z_bf, normw, y_bf);
    gemm_bt<0><<<dim3(16, 64), 256, 0, stream>>>(y_bf, wout_bf, out, 4096, 2048);
}

// Round 3
// 1176.078 us; speedup vs baseline: 1.4236x; 1.4236x over previous
//
#include <hip/hip_runtime.h>

typedef unsigned short u16;
typedef __attribute__((ext_vector_type(4))) float f4;
typedef __attribute__((ext_vector_type(8))) __bf16 bf16x8;
typedef __attribute__((ext_vector_type(4))) float f32x4;

#define D_MODEL 2048
#define D_SSM 4096
#define D_STATE 128
#define NHEADS 64
#define HEADDIM 64
#define CHUNK 64
#define LTOT 4096
#define NB 2
#define CONV_DIM 4352
#define XBC_LD 4480   // 4352 conv channels + 64 dt + 64 pad

__device__ inline float bf2f(unsigned v) { return __uint_as_float(v << 16); }
__device__ inline u16 f2bf(float f) {
    unsigned u = __float_as_uint(f);
    unsigned r = (u + 0x7fffu + ((u >> 16) & 1u)) >> 16;
    return (u16)r;
}
__device__ inline unsigned pack2(float a, float b) {
    return (unsigned)f2bf(a) | ((unsigned)f2bf(b) << 16);
}
__device__ inline void gload_lds16(const void* g, void* l) {
    __builtin_amdgcn_global_load_lds((const __attribute__((address_space(1))) void*)g,
                                     (__attribute__((address_space(3))) void*)l, 16, 0, 0);
}

// ---------------- f32 -> bf16 cast ----------------
__global__ __launch_bounds__(256) void tobf16_kernel(const float* __restrict__ src,
                                                     u16* __restrict__ dst, int n4) {
    int i = blockIdx.x * 256 + threadIdx.x;
    if (i < n4) {
        f4 v = ((const f4*)src)[i];
        uint2 pk;
        pk.x = pack2(v[0], v[1]);
        pk.y = pack2(v[2], v[3]);
        ((uint2*)dst)[i] = pk;
    }
}

// W_in (8512 x 2048) f32 -> win_bf (8576 x 2048) bf16, pad rows zero
__global__ __launch_bounds__(256) void winpad_kernel(const float* __restrict__ src,
                                                     u16* __restrict__ dst) {
    int i = blockIdx.x * 256 + threadIdx.x;
    if (i >= (8576 * 2048 / 4)) return;
    int col4 = i & 511;
    int row = i >> 9;
    f4 v = {0.f, 0.f, 0.f, 0.f};
    if (row < 8512) v = ((const f4*)src)[row * 512 + col4];
    uint2 pk;
    pk.x = pack2(v[0], v[1]);
    pk.y = pack2(v[2], v[3]);
    ((uint2*)dst)[i] = pk;
}

// ---------------- GEMM: C[m,n] = sum_k A[m,k]*B[n,k]; bf16 in; f32 or bf16 out ----
template <int OUT_BF16>
__global__ __launch_bounds__(256) void gemm_bt(const u16* __restrict__ A,
                                               const u16* __restrict__ B,
                                               void* __restrict__ Cp, int K, int ldC) {
    __shared__ u16 As[128 * 32];
    __shared__ u16 Bsm[128 * 32];
    int t = threadIdx.x, w = t >> 6, lane = t & 63;
    int blockM = blockIdx.y * 128, blockN = blockIdx.x * 128;
    int wm = (w & 1) * 64, wn = (w >> 1) * 64;

    const u16* Ab = A + (size_t)(blockM + 32 * w + (lane >> 2)) * K + (lane & 3) * 8;
    const u16* Bb = B + (size_t)(blockN + 32 * w + (lane >> 2)) * K + (lane & 3) * 8;
    u16* AsW = As + w * 1024;
    u16* BsW = Bsm + w * 1024;

    f32x4 acc[4][4] = {};
    const bf16x8* As8 = (const bf16x8*)As;
    const bf16x8* Bs8 = (const bf16x8*)Bsm;
    int aoff = (wm + (lane & 15)) * 4 + (lane >> 4);
    int boff = (wn + (lane & 15)) * 4 + (lane >> 4);

    for (int k0 = 0; k0 < K; k0 += 32) {
        const u16* Ag = Ab + k0;
        const u16* Bg = Bb + k0;
        gload_lds16(Ag, AsW);
        gload_lds16(Ag + (size_t)16 * K, AsW + 512);
        gload_lds16(Bg, BsW);
        gload_lds16(Bg + (size_t)16 * K, BsW + 512);
        __syncthreads();
        bf16x8 af[4], bfv[4];
#pragma unroll
        for (int i = 0; i < 4; i++) af[i] = As8[aoff + 64 * i];
#pragma unroll
        for (int j = 0; j < 4; j++) bfv[j] = Bs8[boff + 64 * j];
#pragma unroll
        for (int i = 0; i < 4; i++)
#pragma unroll
            for (int j = 0; j < 4; j++)
                acc[i][j] = __builtin_amdgcn_mfma_f32_16x16x32_bf16(af[i], bfv[j], acc[i][j], 0, 0, 0);
        __syncthreads();
    }
    int rbase = blockM + wm + (lane >> 4) * 4;
    int cbase = blockN + wn + (lane & 15);
    if (OUT_BF16) {
        u16* C = (u16*)Cp;
#pragma unroll
        for (int i = 0; i < 4; i++)
#pragma unroll
            for (int j = 0; j < 4; j++)
#pragma unroll
                for (int r = 0; r < 4; r++)
                    C[(size_t)(rbase + 16 * i + r) * ldC + cbase + 16 * j] = f2bf(acc[i][j][r]);
    } else {
        float* C = (float*)Cp;
#pragma unroll
        for (int i = 0; i < 4; i++)
#pragma unroll
            for (int j = 0; j < 4; j++)
#pragma unroll
                for (int r = 0; r < 4; r++)
                    C[(size_t)(rbase + 16 * i + r) * ldC + cbase + 16 * j] = acc[i][j][r];
    }
}

// ---------------- depthwise causal conv(4) + bias + silu; bf16 in/out ----------------
__global__ __launch_bounds__(256) void conv_kernel(const u16* __restrict__ xbcdt,
                                                   const float* __restrict__ conv_w,
                                                   const float* __restrict__ conv_b,
                                                   u16* __restrict__ convO) {
    int ch = blockIdx.x * 256 + threadIdx.x;  // 17*256 = 4352 exact
    int row = blockIdx.y;                     // 8192
    int l = row & (LTOT - 1);
    f4 w = *(const f4*)&conv_w[ch * 4];
    float acc = conv_b[ch];
#pragma unroll
    for (int k = 0; k < 4; ++k) {
        int ls = l - 3 + k;
        if (ls >= 0) acc += bf2f(xbcdt[(size_t)(row - 3 + k) * XBC_LD + ch]) * w[k];
    }
    convO[(size_t)row * CONV_DIM + ch] = f2bf(acc / (1.f + __expf(-acc)));
}

// ---------------- dt = softplus(raw + bias) -> dtp[row][h] f32 ----------------
__global__ __launch_bounds__(256) void dt_kernel(const u16* __restrict__ xbcdt,
                                                 const float* __restrict__ dt_bias,
                                                 float* __restrict__ dtp) {
    int idx = blockIdx.x * 256 + threadIdx.x;
    if (idx >= NB * LTOT * NHEADS) return;
    int row = idx >> 6, h = idx & 63;
    float x = bf2f(xbcdt[(size_t)row * XBC_LD + CONV_DIM + h]) + dt_bias[h];
    dtp[idx] = (x > 15.f) ? x : log1pf(__expf(x));
}

// ---------------- CB[l,s] = sum_n C[l,n]*B[s,n] per (b,c) -> CBb f32 ----------------
__global__ __launch_bounds__(256) void cb_kernel(const u16* __restrict__ convO,
                                                 float* __restrict__ CBb) {
    __shared__ u16 Bt[128 * 68];  // [n][s]
    __shared__ u16 Ct[128 * 68];  // [n][l]
    int bc = blockIdx.x;
    int c = bc & 63, b = bc >> 6;
    int rowbase = b * LTOT + c * CHUNK;
    int t = threadIdx.x;
#pragma unroll
    for (int i = 0; i < 32; i++) {
        int idx = i * 256 + t;
        int s = idx >> 7, n = idx & 127;
        Bt[n * 68 + s] = convO[(size_t)(rowbase + s) * CONV_DIM + D_SSM + n];
        Ct[n * 68 + s] = convO[(size_t)(rowbase + s) * CONV_DIM + D_SSM + D_STATE + n];
    }
    __syncthreads();
    int sq = t & 15, lq = t >> 4;
    f4 acc[4] = {};
#pragma unroll 4
    for (int n = 0; n < 128; n++) {
        ushort4 bv = *(const ushort4*)&Bt[n * 68 + sq * 4];
        ushort4 cv = *(const ushort4*)&Ct[n * 68 + lq * 4];
        f4 bf;
        bf[0] = bf2f(bv.x); bf[1] = bf2f(bv.y); bf[2] = bf2f(bv.z); bf[3] = bf2f(bv.w);
        float c0 = bf2f(cv.x), c1 = bf2f(cv.y), c2 = bf2f(cv.z), c3 = bf2f(cv.w);
        acc[0] += c0 * bf; acc[1] += c1 * bf; acc[2] += c2 * bf; acc[3] += c3 * bf;
    }
    float* outb = CBb + (size_t)bc * 4096;
#pragma unroll
    for (int j = 0; j < 4; j++) *(f4*)&outb[(lq * 4 + j) * 64 + sq * 4] = acc[j];
}

// ---------------- fused SSM, MFMA version ----------------
// grid 512 = (b 2) x (h 64) x (pg 4); block 256 (4 waves); sequential over 64 chunks.
// Block owns p' = p - pg*16 in [0,16). State S[16p'][128n] lives in f32 MFMA
// accumulators: wave w owns n in [32w, 32w+32), 2 n-tiles, 8 f32/thread.
__global__ __launch_bounds__(256) void ssm_mfma(const u16* __restrict__ convO,
                                                const float* __restrict__ dtp,
                                                const float* __restrict__ CBb,
                                                const float* __restrict__ A_log,
                                                const float* __restrict__ Dvec,
                                                u16* __restrict__ ybf) {
    __shared__ u16 xT[16 * 72];    // [p'][l]  2304B
    __shared__ u16 BT[128 * 72];   // [n][l]  18432B
    __shared__ u16 Sd[16 * 136];   // [p'][n]  4352B
    __shared__ float dts[64], acs[64], wls[64], els[64];

    int t = threadIdx.x;
    int w = t >> 6, lane = t & 63;
    int z = blockIdx.x;
    int pg = z & 3, h = (z >> 2) & 63, b = z >> 8;
    int pbase = h * 64 + pg * 16;
    float Ah = -__expf(A_log[h]);
    float Dh = Dvec[h];

    int fm = lane & 15;        // within-tile row/col index
    int fq = lane >> 4;        // quad 0..3
    int fk = fq * 8;           // k-base within a 32-wide k-step
    int sl = t & 63;           // staging: row l
    int sq = t >> 6;           // staging: quarter

    f32x4 sacc[2] = {};        // state acc: element (p' = fq*4+r, n = 32w+16nt+fm)

    const float* CBbase = CBb + (size_t)(b * 64) * 4096;

    for (int c = 0; c < 64; ++c) {
        int rowbase = b * LTOT + c * CHUNK;
        const u16* rowp = convO + (size_t)rowbase * CONV_DIM;

        // ---- phase A: scalars (wave 0) + staging (all) ----
        if (t < 64) {
            float dtv = dtp[(size_t)(rowbase + t) * 64 + h];
            float v = dtv * Ah;
#pragma unroll
            for (int off = 1; off < 64; off <<= 1) {
                float pv = __shfl_up(v, off, 64);
                if (t >= off) v += pv;
            }
            float alast = __shfl(v, 63, 64);
            dts[t] = dtv;
            acs[t] = v;
            wls[t] = dtv * __expf(alast - v);
            els[t] = __expf(v);
        }
        {   // xT[p'][l] <- x[l][pbase + p'], 4 u16 per thread
            ushort4 xv = *(const ushort4*)(rowp + (size_t)sl * CONV_DIM + pbase + sq * 4);
            xT[(sq * 4 + 0) * 72 + sl] = xv.x;
            xT[(sq * 4 + 1) * 72 + sl] = xv.y;
            xT[(sq * 4 + 2) * 72 + sl] = xv.z;
            xT[(sq * 4 + 3) * 72 + sl] = xv.w;
        }
        {   // BT[n][l] <- B[l][n], 32 u16 per thread
            const uint4* bp = (const uint4*)(rowp + (size_t)sl * CONV_DIM + D_SSM + sq * 32);
            uint4 bv[4];
#pragma unroll
            for (int q = 0; q < 4; ++q) bv[q] = bp[q];
            const u16* bs = (const u16*)bv;
#pragma unroll
            for (int i = 0; i < 32; ++i) BT[(sq * 32 + i) * 72 + sl] = bs[i];
        }
        {   // Sd[p'][n] <- entering state (bf16)
#pragma unroll
            for (int nt = 0; nt < 2; ++nt)
#pragma unroll
                for (int r = 0; r < 4; ++r)
                    Sd[(fq * 4 + r) * 136 + 32 * w + 16 * nt + fm] = f2bf(sacc[nt][r]);
        }
        __syncthreads();

        // ---- phase C: MFMA compute ----
        int yl = 16 * w + fm;  // A-operand row l for Y mfmas (wave w owns l-rows 16w..16w+15)
        f32x4 yacc = {0.f, 0.f, 0.f, 0.f};

        // Y_off = C . S^T  (A = C from global, B = Sd)
        const u16* Cg = rowp + (size_t)yl * CONV_DIM + D_SSM + D_STATE;
#pragma unroll
        for (int kk = 0; kk < 4; ++kk) {
            bf16x8 afr = *(const bf16x8*)(Cg + kk * 32 + fk);
            bf16x8 bfr = *(const bf16x8*)&Sd[fm * 136 + kk * 32 + fk];
            yacc = __builtin_amdgcn_mfma_f32_16x16x32_bf16(afr, bfr, yacc, 0, 0, 0);
        }
        // scale by exp(acum[l]) per output row
#pragma unroll
        for (int r = 0; r < 4; ++r) yacc[r] *= els[16 * w + fq * 4 + r];

        // Y_diag = G . x   (A = G computed in-register from CB; B = xT)
        {
            const float* CBrow = CBbase + (size_t)c * 4096 + yl * 64;
            float acl = acs[yl];
#pragma unroll
            for (int kk = 0; kk < 2; ++kk) {
                int s0 = kk * 32 + fk;
                f4 cb0 = *(const f4*)&CBrow[s0];
                f4 cb1 = *(const f4*)&CBrow[s0 + 4];
                f4 ac0 = *(const f4*)&acs[s0];
                f4 ac1 = *(const f4*)&acs[s0 + 4];
                f4 dt0 = *(const f4*)&dts[s0];
                f4 dt1 = *(const f4*)&dts[s0 + 4];
                union { u16 us[8]; bf16x8 v; } gu;
#pragma unroll
                for (int j = 0; j < 4; ++j) {
                    int s = s0 + j;
                    float gv = (s <= yl) ? cb0[j] * __expf(acl - ac0[j]) * dt0[j] : 0.f;
                    gu.us[j] = f2bf(gv);
                }
#pragma unroll
                for (int j = 0; j < 4; ++j) {
                    int s = s0 + 4 + j;
                    float gv = (s <= yl) ? cb1[j] * __expf(acl - ac1[j]) * dt1[j] : 0.f;
                    gu.us[4 + j] = f2bf(gv);
                }
                bf16x8 xfr = *(const bf16x8*)&xT[fm * 72 + s0];
                yacc = __builtin_amdgcn_mfma_f32_16x16x32_bf16(gu.v, xfr, yacc, 0, 0, 0);
            }
        }

        // epilogue: += D*x, write y (bf16)
#pragma unroll
        for (int r = 0; r < 4; ++r) {
            int l = 16 * w + fq * 4 + r;
            float xv = bf2f(xT[fm * 72 + l]);
            float yv = yacc[r] + Dh * xv;
            ybf[(size_t)(rowbase + l) * D_SSM + pbase + fm] = f2bf(yv);
        }

        // state update: S = cd*S + (w.x)^T . B
        float cd = els[63];
        sacc[0] *= cd;
        sacc[1] *= cd;
#pragma unroll
        for (int kk = 0; kk < 2; ++kk) {
            int l0 = kk * 32 + fk;
            ushort4 x0 = *(const ushort4*)&xT[fm * 72 + l0];
            ushort4 x1 = *(const ushort4*)&xT[fm * 72 + l0 + 4];
            f4 w0 = *(const f4*)&wls[l0];
            f4 w1 = *(const f4*)&wls[l0 + 4];
            union { u16 us[8]; bf16x8 v; } au;
            au.us[0] = f2bf(bf2f(x0.x) * w0[0]);
            au.us[1] = f2bf(bf2f(x0.y) * w0[1]);
            au.us[2] = f2bf(bf2f(x0.z) * w0[2]);
            au.us[3] = f2bf(bf2f(x0.w) * w0[3]);
            au.us[4] = f2bf(bf2f(x1.x) * w1[0]);
            au.us[5] = f2bf(bf2f(x1.y) * w1[1]);
            au.us[6] = f2bf(bf2f(x1.z) * w1[2]);
            au.us[7] = f2bf(bf2f(x1.w) * w1[3]);
#pragma unroll
            for (int nt = 0; nt < 2; ++nt) {
                bf16x8 bfr = *(const bf16x8*)&BT[(32 * w + 16 * nt + fm) * 72 + l0];
                sacc[nt] = __builtin_amdgcn_mfma_f32_16x16x32_bf16(au.v, bfr, sacc[nt], 0, 0, 0);
            }
        }
        __syncthreads();
    }
}

// ---------------- gate (silu(z)) + RMSNorm, in-place on y_bf ----------------
__global__ __launch_bounds__(256) void gate_norm(const u16* __restrict__ zbf,
                                                 const float* __restrict__ normw,
                                                 u16* __restrict__ ybf) {
    int row = blockIdx.x, t = threadIdx.x;
    const uint2* y2 = (const uint2*)(ybf + (size_t)row * D_SSM);
    const uint2* z2 = (const uint2*)(zbf + (size_t)row * D_SSM);
    f4 yg[4];
    float ss = 0.f;
#pragma unroll
    for (int i = 0; i < 4; ++i) {
        int idx = i * 256 + t;
        uint2 yv = y2[idx], zv = z2[idx];
        float ya[4] = {bf2f(yv.x & 0xffffu), bf2f(yv.x >> 16), bf2f(yv.y & 0xffffu), bf2f(yv.y >> 16)};
        float za[4] = {bf2f(zv.x & 0xffffu), bf2f(zv.x >> 16), bf2f(zv.y & 0xffffu), bf2f(zv.y >> 16)};
        f4 g;
#pragma unroll
        for (int k = 0; k < 4; ++k) {
            float sz = za[k] / (1.f + __expf(-za[k]));
            g[k] = ya[k] * sz;
            ss += g[k] * g[k];
        }
        yg[i] = g;
    }
#pragma unroll
    for (int off = 32; off; off >>= 1) ss += __shfl_down(ss, off, 64);
    __shared__ float red[4];
    if ((t & 63) == 0) red[t >> 6] = ss;
    __syncthreads();
    float tot = red[0] + red[1] + red[2] + red[3];
    float scale = rsqrtf(tot / (float)D_SSM + 1e-5f);
    const f4* nw4 = (const f4*)normw;
    uint2* out = (uint2*)(ybf + (size_t)row * D_SSM);
#pragma unroll
    for (int i = 0; i < 4; ++i) {
        int idx = i * 256 + t;
        f4 v = yg[i] * scale * nw4[idx];
        uint2 pk;
        pk.x = pack2(v[0], v[1]);
        pk.y = pack2(v[2], v[3]);
        out[idx] = pk;
    }
}

// ---------------- launch ----------------
extern "C" void kernel_launch(void* const* d_in, const int* in_sizes, int n_in,
                              void* d_out, int out_size, void* d_ws, size_t ws_size,
                              hipStream_t stream) {
    const float* u = (const float*)d_in[0];
    const float* W_in = (const float*)d_in[1];
    const float* conv_w = (const float*)d_in[2];
    const float* conv_b = (const float*)d_in[3];
    const float* dt_bias = (const float*)d_in[4];
    const float* A_log = (const float*)d_in[5];
    const float* Dv = (const float*)d_in[6];
    const float* normw = (const float*)d_in[7];
    const float* W_out = (const float*)d_in[8];
    float* out = (float*)d_out;
    char* ws = (char*)d_ws;

    // workspace layout (total 216,006,656 B ~= 206 MiB) — same proven layout as round 2
    u16* z_bf = (u16*)(ws + 0ULL);              //  8192x4096 bf16 = 67,108,864
    u16* xbcdt = (u16*)(ws + 67108864ULL);      //  8192x4480 bf16 = 73,400,320
    u16* y_bf = xbcdt;                          //  overlay: 8192x4096 bf16 (xbcdt dead after conv+dt)
    u16* convO = (u16*)(ws + 140509184ULL);     //  8192x4352 bf16 = 71,303,168
    u16* u_bf = convO;                          //  overlay: 33,554,432 (dead before conv writes)
    u16* win_bf = (u16*)(ws + 174063616ULL);    //  overlay: 35,127,296 (dead before conv writes)
    u16* wout_bf = convO;                       //  overlay: 16,777,216 (after ssm)
    float* dtp = (float*)(ws + 211812352ULL);   //  8192x64 f32 = 2,097,152
    float* CBb = (float*)(ws + 213909504ULL);   //  128x64x64 f32 = 2,097,152

    tobf16_kernel<<<16384, 256, 0, stream>>>(u, u_bf, 4194304);
    winpad_kernel<<<17152, 256, 0, stream>>>(W_in, win_bf);
    gemm_bt<1><<<dim3(32, 64), 256, 0, stream>>>(u_bf, win_bf, z_bf, 2048, 4096);
    gemm_bt<1><<<dim3(35, 64), 256, 0, stream>>>(u_bf, win_bf + (size_t)4096 * 2048, xbcdt, 2048, XBC_LD);
    conv_kernel<<<dim3(17, 8192), 256, 0, stream>>>(xbcdt, conv_w, conv_b, convO);
    dt_kernel<<<2048, 256, 0, stream>>>(xbcdt, dt_bias, dtp);
    cb_kernel<<<128, 256, 0, stream>>>(convO, CBb);
    ssm_mfma<<<512, 256, 0, stream>>>(convO, dtp, CBb, A_log, Dv, y_bf);
    tobf16_kernel<<<8192, 256, 0, stream>>>(W_out, wout_bf, 2097152);
    gate_norm<<<8192, 256, 0, stream>>>(z_bf, normw, y_bf);
    gemm_bt<0><<<dim3(16, 64), 256, 0, stream>>>(y_bf, wout_bf, out, 4096, 2048);
}